// Round 1
// baseline (170.100 us; speedup 1.0000x reference)
//
#include <hip/hip_runtime.h>
#include <stdint.h>

typedef unsigned long long u64;

static constexpr int T = 1024;
static constexpr int B = 2;
static constexpr int N = 10000;
static constexpr int L = 30;
static constexpr int S = 2 * L + 1;          // 61
static constexpr int NBLK = 2048;            // sum-of-squares blocks
static constexpr int CBLK = (B * T) / 256;   // 8 correction blocks
static constexpr int NPART = NBLK + CBLK;

static constexpr u64 ALL   = (1ULL << S) - 1;               // bits 0..60
static constexpr u64 EVENM = 0x5555555555555555ULL & ((1ULL << S) - 1);  // blank states

// ws layout: [0, 16384): float partials[NPART]   (8224 B used)
//            [16384, 32768): u64 sel[B*T]        (16384 B)

__device__ __forceinline__ float block_reduce(float s) {
    for (int off = 32; off; off >>= 1) s += __shfl_down(s, off, 64);
    __shared__ float tmp[8];
    int lane = threadIdx.x & 63, w = threadIdx.x >> 6;
    int nw = blockDim.x >> 6;
    if (lane == 0) tmp[w] = s;
    __syncthreads();
    float t = 0.f;
    if (threadIdx.x == 0)
        for (int i = 0; i < nw; ++i) t += tmp[i];
    return t;
}

// Kernel 1: grid-stride sum of squares over all logits (float4),
// plus block 0 computes the CTC lattice sel masks (tiny serial recurrence).
__global__ void k_sumsq(const float4* __restrict__ x, const int* __restrict__ label,
                        float* __restrict__ partials, u64* __restrict__ sel) {
    if (blockIdx.x == 0) {
        int tid = threadIdx.x;
        if (tid < B) {
            int b = tid;
            int lab[L];
            #pragma unroll
            for (int k = 0; k < L; ++k) lab[k] = label[b * L + k];
            // allow2 masks for skip-2 transitions (odd states only; labels >= 1)
            u64 Af = 0, Ab = 0;
            #pragma unroll
            for (int k = 0; k < L; ++k) {
                u64 bit = 1ULL << (2 * k + 1);
                if (k == 0     || lab[k] != lab[k - 1]) Af |= bit;
                if (k == L - 1 || lab[k] != lab[k + 1]) Ab |= bit;
            }
            u64* sb = sel + b * T;
            // forward reachability, t = 0..63 (saturates to ALL by t=60)
            u64 c = 3ULL;
            sb[0] = c;
            for (int t = 1; t < 64; ++t) {
                c = (c | (c << 1) | ((c << 2) & Af)) & ALL;
                sb[t] = c;
            }
            // backward reachability, t = T-1 .. T-64 (saturates to ALL by t=T-61)
            c = (1ULL << (S - 1)) | (1ULL << (S - 2));
            sb[T - 1] = c;
            for (int t = T - 2; t >= T - 64; --t) {
                c = c | (c >> 1) | ((c >> 2) & Ab);
                sb[t] = c;
            }
        }
        // middle rows: both maps saturated -> sel = ALL
        for (int idx = tid; idx < B * T; idx += blockDim.x) {
            int t = idx & (T - 1);
            if (t >= 64 && t < T - 64) sel[idx] = ALL;
        }
    }
    // sum of squares sweep
    const int n4 = (T * B * N) / 4;   // 5,120,000
    float s = 0.f;
    for (int i = blockIdx.x * blockDim.x + threadIdx.x; i < n4;
         i += gridDim.x * blockDim.x) {
        float4 v = x[i];
        s += v.x * v.x + v.y * v.y + v.z * v.z + v.w * v.w;
    }
    float tot = block_reduce(s);
    if (threadIdx.x == 0) partials[blockIdx.x] = tot;
}

// Kernel 2: masked correction. One thread per (b,t); dedupe repeated vocab ids
// (scatter-max semantics: blank counted once, repeated labels counted once).
__global__ void k_corr(const float* __restrict__ logits, const int* __restrict__ label,
                       const u64* __restrict__ sel, float* __restrict__ partials) {
    int id = blockIdx.x * blockDim.x + threadIdx.x;   // 0 .. B*T-1
    int b = id >> 10;          // id / T
    int t = id & (T - 1);      // id % T
    u64 m = sel[id];
    const float* row = logits + (size_t)t * (B * N) + (size_t)b * N;
    float s = 0.f;
    if (m & EVENM) { float v = row[0]; s += v * v; }   // blank (v=0) once
    int lab[L];
    const int* lb = label + b * L;
    #pragma unroll
    for (int k = 0; k < L; ++k) lab[k] = lb[k];
    for (int k = 0; k < L; ++k) {
        if (m & (1ULL << (2 * k + 1))) {
            int v = lab[k];
            bool dup = false;
            for (int k2 = 0; k2 < k; ++k2)
                if ((m & (1ULL << (2 * k2 + 1))) && lab[k2] == v) { dup = true; break; }
            if (!dup) { float xv = row[v]; s += xv * xv; }
        }
    }
    float tot = block_reduce(s);
    if (threadIdx.x == 0) partials[NBLK + blockIdx.x] = -tot;
}

// Kernel 3: out = 0.5 * (sum_sq - corr)
__global__ void k_final(const float* __restrict__ partials, float* __restrict__ out) {
    float s = 0.f;
    for (int i = threadIdx.x; i < NPART; i += blockDim.x) s += partials[i];
    float tot = block_reduce(s);
    if (threadIdx.x == 0) out[0] = 0.5f * tot;
}

extern "C" void kernel_launch(void* const* d_in, const int* in_sizes, int n_in,
                              void* d_out, int out_size, void* d_ws, size_t ws_size,
                              hipStream_t stream) {
    const float* logits = (const float*)d_in[0];
    const int*   label  = (const int*)d_in[2];
    float* partials = (float*)d_ws;
    u64*   sel      = (u64*)((char*)d_ws + 16384);

    k_sumsq<<<NBLK, 256, 0, stream>>>((const float4*)logits, label, partials, sel);
    k_corr<<<CBLK, 256, 0, stream>>>(logits, label, sel, partials);
    k_final<<<1, 256, 0, stream>>>(partials, (float*)d_out);
}

// Round 2
// 141.044 us; speedup vs baseline: 1.2060x; 1.2060x over previous
//
#include <hip/hip_runtime.h>
#include <stdint.h>

typedef unsigned long long u64;

static constexpr int T = 1024;
static constexpr int B = 2;
static constexpr int N = 10000;
static constexpr int L = 30;
static constexpr int S = 2 * L + 1;   // 61

static constexpr int CORR_BLK = 256;   // blocks 0..255: correction, 8 (b,t)/block
static constexpr int SUM_BLK  = 2048;  // blocks 256..2303: sum-of-squares sweep
static constexpr int NBLK     = CORR_BLK + SUM_BLK;

static constexpr u64 ALL   = (1ULL << S) - 1;
static constexpr u64 EVENM = 0x5555555555555555ULL & ((1ULL << S) - 1);

__device__ __forceinline__ float block_reduce(float s) {
    for (int off = 32; off; off >>= 1) s += __shfl_down(s, off, 64);
    __shared__ float tmp[8];
    int lane = threadIdx.x & 63, w = threadIdx.x >> 6;
    int nw = blockDim.x >> 6;
    if (lane == 0) tmp[w] = s;
    __syncthreads();
    float t = 0.f;
    if (threadIdx.x == 0)
        for (int i = 0; i < nw; ++i) t += tmp[i];
    return t;
}

// Fused: correction blocks compute their own lattice masks (<=64 bit-op steps
// per (b,t)); sweep blocks do float4 sum-of-squares. Each block atomically adds
// its signed partial (x0.5 at the end) into out[0].
__global__ void k_fused(const float4* __restrict__ x4, const float* __restrict__ x,
                        const int* __restrict__ label, float* __restrict__ out) {
    float s = 0.f;
    if (blockIdx.x < CORR_BLK) {
        __shared__ int labs[B][L];
        __shared__ u64 dups[B][L];
        __shared__ u64 AfS[B], AbS[B];
        int tid = threadIdx.x;
        if (tid < B) {
            int b = tid;
            int lb[L];
            u64 Af = 0, Ab = 0;
            #pragma unroll
            for (int k = 0; k < L; ++k) { lb[k] = label[b * L + k]; labs[b][k] = lb[k]; }
            #pragma unroll
            for (int k = 0; k < L; ++k) {
                u64 bit = 1ULL << (2 * k + 1);
                if (k == 0     || lb[k] != lb[k - 1]) Af |= bit;
                if (k == L - 1 || lb[k] != lb[k + 1]) Ab |= bit;
                u64 d = 0;
                for (int k2 = 0; k2 < k; ++k2)
                    if (lb[k2] == lb[k]) d |= 1ULL << (2 * k2 + 1);
                dups[b][k] = d;
            }
            AfS[b] = Af; AbS[b] = Ab;
        }
        __syncthreads();
        int pair = blockIdx.x * 8 + (tid >> 5);   // 0 .. 2047  == b*T + t
        int lane = tid & 31;
        int b = pair >> 10;
        int t = pair & (T - 1);
        u64 m;
        if (t < 64) {
            // backward map saturated (t <= T-61); forward needs t steps
            u64 Af = AfS[b];
            u64 c = 3ULL;
            for (int i = 0; i < t; ++i) c = (c | (c << 1) | ((c << 2) & Af)) & ALL;
            m = c;
        } else if (t >= T - 64) {
            // forward map saturated (t >= 60); backward needs T-1-t steps
            u64 Ab = AbS[b];
            u64 c = (1ULL << (S - 1)) | (1ULL << (S - 2));
            int n = T - 1 - t;
            for (int i = 0; i < n; ++i) c = c | (c >> 1) | ((c >> 2) & Ab);
            m = c;
        } else {
            m = ALL;
        }
        const float* row = x + (size_t)t * (B * N) + (size_t)b * N;
        if (lane < L) {
            u64 bit = 1ULL << (2 * lane + 1);
            if ((m & bit) && !(m & dups[b][lane])) {
                float v = row[labs[b][lane]];
                s -= v * v;
            }
        } else if (lane == L) {
            if (m & EVENM) { float v = row[0]; s -= v * v; }  // blank, counted once
        }
    } else {
        const int n4 = (T * B * N) / 4;   // 5,120,000
        int base = (blockIdx.x - CORR_BLK) * blockDim.x + threadIdx.x;
        for (int i = base; i < n4; i += SUM_BLK * 256) {
            float4 v = x4[i];
            s += v.x * v.x + v.y * v.y + v.z * v.z + v.w * v.w;
        }
    }
    float tot = block_reduce(s);
    if (threadIdx.x == 0) atomicAdd(out, 0.5f * tot);
}

extern "C" void kernel_launch(void* const* d_in, const int* in_sizes, int n_in,
                              void* d_out, int out_size, void* d_ws, size_t ws_size,
                              hipStream_t stream) {
    const float* logits = (const float*)d_in[0];
    const int*   label  = (const int*)d_in[2];
    float* out = (float*)d_out;

    hipMemsetAsync(out, 0, sizeof(float), stream);
    k_fused<<<NBLK, 256, 0, stream>>>((const float4*)logits, logits, label, out);
}

// Round 3
// 120.283 us; speedup vs baseline: 1.4142x; 1.1726x over previous
//
#include <hip/hip_runtime.h>
#include <stdint.h>

typedef unsigned long long u64;

static constexpr int T = 1024;
static constexpr int B = 2;
static constexpr int N = 10000;
static constexpr int L = 30;
static constexpr int S = 2 * L + 1;   // 61

static constexpr int SUM_BLK  = 1792;  // blocks 0..1791: sum-of-squares sweep
static constexpr int CORR_BLK = 256;   // blocks 1792..2047: correction, 8 (b,t)/block
static constexpr int NBLK     = SUM_BLK + CORR_BLK;   // 2048 = exactly one resident round

static constexpr u64 ALL   = (1ULL << S) - 1;
static constexpr u64 EVENM = 0x5555555555555555ULL & ((1ULL << S) - 1);

__device__ __forceinline__ float block_reduce(float s) {
    for (int off = 32; off; off >>= 1) s += __shfl_down(s, off, 64);
    __shared__ float tmp[8];
    int lane = threadIdx.x & 63, w = threadIdx.x >> 6;
    int nw = blockDim.x >> 6;
    if (lane == 0) tmp[w] = s;
    __syncthreads();
    float t = 0.f;
    if (threadIdx.x == 0)
        for (int i = 0; i < nw; ++i) t += tmp[i];
    return t;
}

__device__ __forceinline__ float sq4(float4 v) {
    return v.x * v.x + v.y * v.y + v.z * v.z + v.w * v.w;
}

// One fused kernel; each block writes its signed partial to partials[blockIdx.x].
// No same-address atomics (round-2 lesson: 2304 same-address atomicAdds ~= 50us).
__global__ void k_fused(const float4* __restrict__ x4, const float* __restrict__ x,
                        const int* __restrict__ label, float* __restrict__ partials) {
    float s = 0.f;
    if (blockIdx.x < SUM_BLK) {
        const int n4 = (T * B * N) / 4;   // 5,120,000
        const int stride = SUM_BLK * 256; // 458,752 -> ~11.16 float4/thread
        int i0 = blockIdx.x * 256 + threadIdx.x;
        // 4 independent load streams per iteration, predicated at the boundary
        for (int i = i0; i < n4; i += 4 * stride) {
            int i1 = i + stride, i2 = i + 2 * stride, i3 = i + 3 * stride;
            float4 a = x4[i];
            float4 b = (i1 < n4) ? x4[i1] : make_float4(0.f, 0.f, 0.f, 0.f);
            float4 c = (i2 < n4) ? x4[i2] : make_float4(0.f, 0.f, 0.f, 0.f);
            float4 d = (i3 < n4) ? x4[i3] : make_float4(0.f, 0.f, 0.f, 0.f);
            s += sq4(a) + sq4(b) + sq4(c) + sq4(d);
        }
    } else {
        __shared__ int labs[B][L];
        __shared__ u64 dups[B][L];
        __shared__ u64 AfS[B], AbS[B];
        int tid = threadIdx.x;
        if (tid < B) {
            int b = tid;
            int lb[L];
            u64 Af = 0, Ab = 0;
            #pragma unroll
            for (int k = 0; k < L; ++k) { lb[k] = label[b * L + k]; labs[b][k] = lb[k]; }
            #pragma unroll
            for (int k = 0; k < L; ++k) {
                u64 bit = 1ULL << (2 * k + 1);
                if (k == 0     || lb[k] != lb[k - 1]) Af |= bit;
                if (k == L - 1 || lb[k] != lb[k + 1]) Ab |= bit;
                u64 d = 0;
                for (int k2 = 0; k2 < k; ++k2)
                    if (lb[k2] == lb[k]) d |= 1ULL << (2 * k2 + 1);
                dups[b][k] = d;
            }
            AfS[b] = Af; AbS[b] = Ab;
        }
        __syncthreads();
        int pair = (blockIdx.x - SUM_BLK) * 8 + (tid >> 5);   // 0..2047 == b*T + t
        int lane = tid & 31;
        int b = pair >> 10;
        int t = pair & (T - 1);
        u64 m;
        if (t < 64) {
            // backward map saturated (t <= T-61); forward needs t steps
            u64 Af = AfS[b];
            u64 c = 3ULL;
            for (int i = 0; i < t; ++i) c = (c | (c << 1) | ((c << 2) & Af)) & ALL;
            m = c;
        } else if (t >= T - 64) {
            // forward map saturated (t >= 60); backward needs T-1-t steps
            u64 Ab = AbS[b];
            u64 c = (1ULL << (S - 1)) | (1ULL << (S - 2));
            int n = T - 1 - t;
            for (int i = 0; i < n; ++i) c = c | (c >> 1) | ((c >> 2) & Ab);
            m = c;
        } else {
            m = ALL;
        }
        const float* row = x + (size_t)t * (B * N) + (size_t)b * N;
        if (lane < L) {
            u64 bit = 1ULL << (2 * lane + 1);
            if ((m & bit) && !(m & dups[b][lane])) {
                float v = row[labs[b][lane]];
                s -= v * v;
            }
        } else if (lane == L) {
            if (m & EVENM) { float v = row[0]; s -= v * v; }  // blank, counted once
        }
    }
    float tot = block_reduce(s);
    if (threadIdx.x == 0) partials[blockIdx.x] = tot;
}

// out = 0.5 * sum(partials)
__global__ void k_final(const float* __restrict__ partials, float* __restrict__ out) {
    float s = 0.f;
    for (int i = threadIdx.x; i < NBLK; i += 256) s += partials[i];
    float tot = block_reduce(s);
    if (threadIdx.x == 0) out[0] = 0.5f * tot;
}

extern "C" void kernel_launch(void* const* d_in, const int* in_sizes, int n_in,
                              void* d_out, int out_size, void* d_ws, size_t ws_size,
                              hipStream_t stream) {
    const float* logits = (const float*)d_in[0];
    const int*   label  = (const int*)d_in[2];
    float* partials = (float*)d_ws;

    k_fused<<<NBLK, 256, 0, stream>>>((const float4*)logits, logits, label, partials);
    k_final<<<1, 256, 0, stream>>>(partials, (float*)d_out);
}

// Round 4
// 118.761 us; speedup vs baseline: 1.4323x; 1.0128x over previous
//
#include <hip/hip_runtime.h>
#include <stdint.h>

typedef unsigned long long u64;

static constexpr int T = 1024;
static constexpr int B = 2;
static constexpr int N = 10000;
static constexpr int L = 30;
static constexpr int S = 2 * L + 1;   // 61

static constexpr int NBLK  = 2048;    // all blocks sweep; blocks 0..255 also do corr
static constexpr int CHUNK = 2500;    // float4 per block; 2048*2500 == 5,120,000 == T*B*N/4
static constexpr int TAIL  = CHUNK - 9 * 256;   // 196

static constexpr u64 ALL   = (1ULL << S) - 1;
static constexpr u64 EVENM = 0x5555555555555555ULL & ((1ULL << S) - 1);

__device__ __forceinline__ float block_reduce(float s) {
    for (int off = 32; off; off >>= 1) s += __shfl_down(s, off, 64);
    __shared__ float tmp[8];
    int lane = threadIdx.x & 63, w = threadIdx.x >> 6;
    int nw = blockDim.x >> 6;
    if (lane == 0) tmp[w] = s;
    __syncthreads();
    float t = 0.f;
    if (threadIdx.x == 0)
        for (int i = 0; i < nw; ++i) t += tmp[i];
    return t;
}

__device__ __forceinline__ float sq4(float4 v) {
    return v.x * v.x + v.y * v.y + v.z * v.z + v.w * v.w;
}

// All 2048 blocks sweep one contiguous 2500-float4 chunk (perfect balance, no
// boundary predication except the 196-thread tail). Blocks 0..255 additionally
// compute the CTC-lattice masked correction FIRST (1 scattered load/thread,
// overlapped with the streaming sweep). Partials per block; no same-address
// atomics (round-2 lesson).
__global__ void k_fused(const float4* __restrict__ x4, const float* __restrict__ x,
                        const int* __restrict__ label, float* __restrict__ partials) {
    float s = 0.f;
    int tid = threadIdx.x;

    if (blockIdx.x < 256) {
        __shared__ int labs[B][L];
        __shared__ u64 dups[B][L];
        __shared__ u64 AfS[B], AbS[B];
        if (tid < B) {
            int b = tid;
            int lb[L];
            u64 Af = 0, Ab = 0;
            #pragma unroll
            for (int k = 0; k < L; ++k) { lb[k] = label[b * L + k]; labs[b][k] = lb[k]; }
            #pragma unroll
            for (int k = 0; k < L; ++k) {
                u64 bit = 1ULL << (2 * k + 1);
                if (k == 0     || lb[k] != lb[k - 1]) Af |= bit;
                if (k == L - 1 || lb[k] != lb[k + 1]) Ab |= bit;
                u64 d = 0;
                for (int k2 = 0; k2 < k; ++k2)
                    if (lb[k2] == lb[k]) d |= 1ULL << (2 * k2 + 1);
                dups[b][k] = d;
            }
            AfS[b] = Af; AbS[b] = Ab;
        }
        __syncthreads();
        int pair = blockIdx.x * 8 + (tid >> 5);   // 0..2047 == b*T + t
        int lane = tid & 31;
        int b = pair >> 10;
        int t = pair & (T - 1);
        u64 m;
        if (t < 64) {
            // backward map saturated (t <= T-61); forward needs t steps
            u64 Af = AfS[b];
            u64 c = 3ULL;
            for (int i = 0; i < t; ++i) c = (c | (c << 1) | ((c << 2) & Af)) & ALL;
            m = c;
        } else if (t >= T - 64) {
            // forward map saturated (t >= 60); backward needs T-1-t steps
            u64 Ab = AbS[b];
            u64 c = (1ULL << (S - 1)) | (1ULL << (S - 2));
            int n = T - 1 - t;
            for (int i = 0; i < n; ++i) c = c | (c >> 1) | ((c >> 2) & Ab);
            m = c;
        } else {
            m = ALL;
        }
        const float* row = x + (size_t)t * (B * N) + (size_t)b * N;
        if (lane < L) {
            u64 bit = 1ULL << (2 * lane + 1);
            if ((m & bit) && !(m & dups[b][lane])) {
                float v = row[labs[b][lane]];
                s -= v * v;
            }
        } else if (lane == L) {
            if (m & EVENM) { float v = row[0]; s -= v * v; }  // blank, counted once
        }
    }

    // Sweep: contiguous chunk, 9 full rounds + 196-thread tail; two 5-deep
    // independent load batches (MLP 5, VGPR-friendly).
    const float4* p = x4 + (size_t)blockIdx.x * CHUNK + tid;
    float4 v[5];
    #pragma unroll
    for (int j = 0; j < 5; ++j) v[j] = p[j * 256];
    #pragma unroll
    for (int j = 0; j < 5; ++j) s += sq4(v[j]);
    #pragma unroll
    for (int j = 0; j < 4; ++j) v[j] = p[(5 + j) * 256];
    v[4] = (tid < TAIL) ? p[9 * 256] : make_float4(0.f, 0.f, 0.f, 0.f);
    #pragma unroll
    for (int j = 0; j < 5; ++j) s += sq4(v[j]);

    float tot = block_reduce(s);
    if (threadIdx.x == 0) partials[blockIdx.x] = tot;
}

// out = 0.5 * sum(partials)
__global__ void k_final(const float* __restrict__ partials, float* __restrict__ out) {
    float s = 0.f;
    for (int i = threadIdx.x; i < NBLK; i += 256) s += partials[i];
    float tot = block_reduce(s);
    if (threadIdx.x == 0) out[0] = 0.5f * tot;
}

extern "C" void kernel_launch(void* const* d_in, const int* in_sizes, int n_in,
                              void* d_out, int out_size, void* d_ws, size_t ws_size,
                              hipStream_t stream) {
    const float* logits = (const float*)d_in[0];
    const int*   label  = (const int*)d_in[2];
    float* partials = (float*)d_ws;

    k_fused<<<NBLK, 256, 0, stream>>>((const float4*)logits, logits, label, partials);
    k_final<<<1, 256, 0, stream>>>(partials, (float*)d_out);
}